// Round 1
// baseline (217.077 us; speedup 1.0000x reference)
//
#include <hip/hip_runtime.h>
#include <math.h>

// Problem constants (from reference)
#define BATCH     2
#define NLAB      256            // 64 bifs * 4 stubs
#define VOX       (192*192*192)  // 7,077,888 voxels per batch
#define TEMP      0.2f
#define GRIDX     768            // blocks per batch; 1536 total = 6 blocks/CU
#define NITER     (VOX / (GRIDX * 1024))   // = 9 exact (1024 voxels/block-iter)
#define NPART     16             // reduce parts per batch

// Per-block slot packing: value = sum_fg + STEP*count. At GRIDX=768 a block
// sees 9216 voxels (~36/bin, max ~150): packed <= ~600K << 2^24 -> count
// decodes exactly; fg fractional error <= ~0.03 abs per slot -> ~1e-4 rel
// on batch-bin sums (threshold 1e-2; same scheme measured absmax 0.0 at R7).
#define STEP      4096.0f
#define INV_STEP  (1.0f/4096.0f)

typedef unsigned int u32;
typedef __attribute__((ext_vector_type(8))) short bf16x8;   // 8 bf16 (4 VGPRs)
typedef __attribute__((ext_vector_type(4))) float f32x4;    // MFMA C/D
union FragU { uint4 u; bf16x8 v; };

// fg = softmax(pred, ch)[1] = sigmoid(p1-p0) since C == 2.
// Pack (label<<24) | bf16_rne(fg) into one u32 per voxel.
__device__ __forceinline__ u32 packvox(float pa, float pc, float pl) {
    const float fg = 1.0f / (1.0f + __expf(pa - pc));
    u32 bits = __float_as_uint(fg);
    bits += 0x7FFFu + ((bits >> 16) & 1u);            // RNE to bf16
    const u32 lab = ((u32)(int)(pl + 0.5f)) & 255u;
    return (lab << 24) | (bits >> 16);
}

// Build one packed-bf16 word (2 K-slots: even 'de', odd 'dodd') of each of the
// three fragments: A = [hi==m], B1 = [lo==m], B2 = [lo==m]*fg.
// mlane = lane&15 (A row index / B col index). 0x3F80 = bf16 1.0.
#define PAIR(de, dodd, aw, b1w, b2w) do {                                   \
    const u32 _e = (de), _o = (dodd);                                       \
    const bool he  = ((_e >> 28) == mlane);                                 \
    const bool ho  = ((_o >> 28) == mlane);                                 \
    const bool le  = (((_e >> 24) & 15u) == mlane);                         \
    const bool lo_ = (((_o >> 24) & 15u) == mlane);                         \
    aw  = (he ? 0x00003F80u : 0u) | (ho  ? 0x3F800000u : 0u);               \
    b1w = (le ? 0x00003F80u : 0u) | (lo_ ? 0x3F800000u : 0u);               \
    b2w = (le ? (_e & 0xFFFFu) : 0u) | (lo_ ? (_o << 16) : 0u);             \
} while (0)

// ---------------------------------------------------------------------------
// Kernel 1: histogram via one-hot outer-product MFMA (NO atomics).
// bin = hi4*16 + lo4. Per 32-voxel tile: counts += Phi^T*Plo (16x16x32 bf16
// MFMA), sums += Phi^T*(fg*Plo). The serial ds_add_f32 pipe (3.3 cyc/lane-op,
// the R1-R8 bottleneck) is eliminated; cost moves to wave-parallel VALU
// (~2.7 instr/voxel ~ 1.35 cyc/voxel/CU). Each wave stages 256 voxels
// (label|fg packed u32) in wave-private LDS, then 8 tiles of broadcast
// ds_read_b128 (16 lanes/group share addresses -> conflict-free).
// Counts are exact f32 integers; fg carries bf16 RNE error (~2^-9 rel).
// ---------------------------------------------------------------------------
__global__ __launch_bounds__(256, 4) void histo_kernel(
    const float* __restrict__ pred,     // [B,2,V]
    const float* __restrict__ labmap,   // [B,1,V]
    float* __restrict__ ws_slots)       // [B*GRIDX][256] packed per-block hist
{
    __shared__ __align__(16) u32 s_stage[4][2][256];  // per-wave, double-buffer
    __shared__ float s_cnt[4][NLAB];
    __shared__ float s_sum[4][NLAB];

    const int b    = blockIdx.y;
    const int tid  = threadIdx.x;
    const int w    = tid >> 6;          // wave id 0..3
    const int lane = tid & 63;
    const u32 mlane = (u32)(lane & 15); // A row / B col owned by this lane
    const int g    = lane >> 4;         // K-group 0..3

    const float4* p0 = (const float4*)(pred + (size_t)b * 2 * VOX);
    const float4* p1 = (const float4*)(pred + (size_t)b * 2 * VOX + VOX);
    const float4* lm = (const float4*)(labmap + (size_t)b * VOX);

    f32x4 accC = {0.f, 0.f, 0.f, 0.f};  // counts C[16][16]
    f32x4 accS = {0.f, 0.f, 0.f, 0.f};  // fg sums C[16][16]

    const int base = blockIdx.x * 256 + tid;

    #pragma unroll 2
    for (int it = 0; it < NITER; ++it) {
        const int i = base + it * (GRIDX * 256);
        const float4 a = p0[i];   // channel 0
        const float4 c = p1[i];   // channel 1
        const float4 l = lm[i];   // labels (exact integers 0..255 as float)

        uint4 pkv;
        pkv.x = packvox(a.x, c.x, l.x);
        pkv.y = packvox(a.y, c.y, l.y);
        pkv.z = packvox(a.z, c.z, l.z);
        pkv.w = packvox(a.w, c.w, l.w);

        u32* st = &s_stage[w][it & 1][0];
        *(uint4*)(st + (lane << 2)) = pkv;   // wave-private: no barrier needed

        const u32* rp = st + (g << 3);       // this lane's K-group base
        #pragma unroll
        for (int t = 0; t < 8; ++t) {
            const uint4 q0 = *(const uint4*)(rp + t * 32);      // slots 0..3
            const uint4 q1 = *(const uint4*)(rp + t * 32 + 4);  // slots 4..7
            u32 a0, a1, a2, a3, b10, b11, b12, b13, b20, b21, b22, b23;
            PAIR(q0.x, q0.y, a0, b10, b20);
            PAIR(q0.z, q0.w, a1, b11, b21);
            PAIR(q1.x, q1.y, a2, b12, b22);
            PAIR(q1.z, q1.w, a3, b13, b23);
            FragU A, B1, B2;
            A.u  = make_uint4(a0, a1, a2, a3);
            B1.u = make_uint4(b10, b11, b12, b13);
            B2.u = make_uint4(b20, b21, b22, b23);
            accC = __builtin_amdgcn_mfma_f32_16x16x32_bf16(A.v, B1.v, accC, 0, 0, 0);
            accS = __builtin_amdgcn_mfma_f32_16x16x32_bf16(A.v, B2.v, accS, 0, 0, 0);
        }
    }

    // C/D layout (m89-verified): col = lane&15, row = (lane>>4)*4 + reg.
    // bin = row*16 + col  (row = hi nibble via A, col = lo nibble via B).
    const int row0 = (lane >> 4) << 2;
    const int colb = lane & 15;
    #pragma unroll
    for (int j = 0; j < 4; ++j) {
        s_cnt[w][(row0 + j) * 16 + colb] = accC[j];
        s_sum[w][(row0 + j) * 16 + colb] = accS[j];
    }
    __syncthreads();

    // Fold 4 waves, write packed slot (coalesced, unconditional).
    const float cs = s_cnt[0][tid] + s_cnt[1][tid] + s_cnt[2][tid] + s_cnt[3][tid];
    const float ss = s_sum[0][tid] + s_sum[1][tid] + s_sum[2][tid] + s_sum[3][tid];
    ws_slots[((size_t)(b * GRIDX + blockIdx.x)) * NLAB + tid] = ss + STEP * cs;
}

// ---------------------------------------------------------------------------
// Kernel 2: parallel slot reduction. Block r: batch = r/NPART, part = r%NPART;
// 256 threads = bins. Decode + sum GRIDX/NPART slots (coalesced 1KB rows).
// ---------------------------------------------------------------------------
__global__ __launch_bounds__(256) void reduce_kernel(
    const float* __restrict__ ws_slots, // [B*GRIDX][256]
    float* __restrict__ psum,           // [B*NPART][256]
    float* __restrict__ pcnt)           // [B*NPART][256]
{
    const int bin  = threadIdx.x;
    const int b    = blockIdx.x / NPART;
    const int part = blockIdx.x % NPART;
    const int per  = GRIDX / NPART;

    float cs = 0.0f, ss = 0.0f;
    for (int s = part * per; s < (part + 1) * per; ++s) {
        float v = ws_slots[((size_t)(b * GRIDX + s)) * NLAB + bin];
        float c = floorf(v * INV_STEP + 0.5f);   // exact count decode
        cs += c;
        ss += v - c * STEP;                      // packed fg sum
    }
    psum[(size_t)blockIdx.x * NLAB + bin] = ss;
    pcnt[(size_t)blockIdx.x * NLAB + bin] = cs;
}

// ---------------------------------------------------------------------------
// Kernel 3: fold partials, then masked softmin -> scalar loss.
// ---------------------------------------------------------------------------
__global__ __launch_bounds__(256) void scalar_kernel(
    const float* __restrict__ psum,     // [B*NPART][256]
    const float* __restrict__ pcnt,
    float* __restrict__ out)            // [1] loss
{
    __shared__ float s_fsum[BATCH][NLAB];
    __shared__ float s_fcnt[BATCH][NLAB];

    const int tid = threadIdx.x;        // 256 threads = bins

    for (int b = 0; b < BATCH; ++b) {
        float ss = 0.0f, cs = 0.0f;
        for (int p = 0; p < NPART; ++p) {
            ss += psum[(size_t)(b * NPART + p) * NLAB + tid];
            cs += pcnt[(size_t)(b * NPART + p) * NLAB + tid];
        }
        s_fsum[b][tid] = ss;
        s_fcnt[b][tid] = cs;
    }
    __syncthreads();

    if (tid < 64) {
        float total = 0.0f;
        float nbifs = 0.0f;
        if (tid >= 1) {  // bifs 1..63 (reference drops bif 0)
            for (int bb = 0; bb < BATCH; ++bb) {
                float means[3];
                bool  valid[3];
                int   nvalid = 0;
                for (int s = 0; s < 3; ++s) {
                    int lab = tid * 4 + 1 + s;   // stub s+1 (stub 0 dropped)
                    float cnt = s_fcnt[bb][lab];
                    float sum = s_fsum[bb][lab];
                    valid[s] = (cnt >= 1.0f);            // MIN_VOXELS = 1
                    means[s] = sum / fmaxf(cnt, 1.0f);
                    nvalid  += valid[s] ? 1 : 0;
                }
                float logits[3], m = -3e38f;
                for (int s = 0; s < 3; ++s) {
                    logits[s] = valid[s] ? (-means[s] / TEMP) : -1e9f;
                    m = fmaxf(m, logits[s]);
                }
                float e[3], se = 0.0f;
                for (int s = 0; s < 3; ++s) { e[s] = __expf(logits[s] - m); se += e[s]; }
                float score = 0.0f;
                for (int s = 0; s < 3; ++s) {
                    if (valid[s]) score += means[s] * (e[s] / se);
                }
                if (nvalid >= 2) {  // MIN_STUBS = 2
                    total += 1.0f - score;
                    nbifs += 1.0f;
                }
            }
        }
        for (int off = 32; off > 0; off >>= 1) {
            total += __shfl_down(total, off);
            nbifs += __shfl_down(nbifs, off);
        }
        if (tid == 0) {
            out[0] = (nbifs > 0.0f) ? (total / fmaxf(nbifs, 1.0f)) : 0.0f;
        }
    }
}

// ---------------------------------------------------------------------------
extern "C" void kernel_launch(void* const* d_in, const int* in_sizes, int n_in,
                              void* d_out, int out_size, void* d_ws, size_t ws_size,
                              hipStream_t stream) {
    const float* pred = (const float*)d_in[0];   // [B,C,D,H,W] fp32
    const float* lab  = (const float*)d_in[1];   // [B,1,D,H,W] fp32

    float* ws_slots = (float*)d_ws;                          // [B*GRIDX][256]
    float* psum = ws_slots + (size_t)BATCH * GRIDX * NLAB;   // [B*NPART][256]
    float* pcnt = psum + (size_t)BATCH * NPART * NLAB;       // [B*NPART][256]

    dim3 grid(GRIDX, BATCH);
    histo_kernel<<<grid, 256, 0, stream>>>(pred, lab, ws_slots);
    reduce_kernel<<<BATCH * NPART, 256, 0, stream>>>(ws_slots, psum, pcnt);
    scalar_kernel<<<1, 256, 0, stream>>>(psum, pcnt, (float*)d_out);
}